// Round 1
// baseline (1581.800 us; speedup 1.0000x reference)
//
#include <hip/hip_runtime.h>
#include <hip/hip_bf16.h>
#include <cstdint>
#include <cstddef>

// Problem constants (match reference setup_inputs)
#define D_MODEL 1024
#define NHEADS  16
#define DKH     64      // d_k per head
#define BB      2
#define SS      2048
#define MM      (BB*SS) // 4096 rows total

// ---------------------------------------------------------------------------
// K1: fused QKV projection.  out[b,h,s,dk] = sum_d X[b,s,d] * W[h*64+dk, d]
// GEMM-NT: A (M=4096 x K=1024) row-major, W (N=1024 x K=1024) row-major.
// 64x64 tile, K-tile 16, 256 threads, 4x4 microtile.
// gridDim.z selects which of {Q,K,V} projection this block computes.
// ---------------------------------------------------------------------------
__global__ __launch_bounds__(256)
void k_qkv_proj(const float* __restrict__ Qi, const float* __restrict__ Ki,
                const float* __restrict__ Vi,
                const float* __restrict__ WQ, const float* __restrict__ WK,
                const float* __restrict__ WV,
                float* __restrict__ qb, float* __restrict__ kb,
                float* __restrict__ vb)
{
    const int z = blockIdx.z;
    const float* __restrict__ X = (z == 0) ? Qi : (z == 1) ? Ki : Vi;
    const float* __restrict__ W = (z == 0) ? WQ : (z == 1) ? WK : WV;
    float* __restrict__ O       = (z == 0) ? qb : (z == 1) ? kb : vb;

    const int n0 = blockIdx.x * 64;
    const int m0 = blockIdx.y * 64;
    const int tx = threadIdx.x, ty = threadIdx.y;
    const int tid = ty * 16 + tx;

    // k-major LDS tiles: As[kk][row], row-stride 68 keeps float4 alignment,
    // 68 mod 32 = 4 -> worst 2-way bank aliasing (free on CDNA4).
    __shared__ float As[16][68];
    __shared__ float Bs[16][68];

    float acc[4][4] = {};

    const int lr = tid >> 2;        // 0..63 (tile row)
    const int lc = (tid & 3) * 4;   // 0,4,8,12 (k offset)

    for (int k0 = 0; k0 < D_MODEL; k0 += 16) {
        float4 av = *(const float4*)(X + (size_t)(m0 + lr) * D_MODEL + k0 + lc);
        float4 bv = *(const float4*)(W + (size_t)(n0 + lr) * D_MODEL + k0 + lc);
        __syncthreads();
        As[lc + 0][lr] = av.x; As[lc + 1][lr] = av.y;
        As[lc + 2][lr] = av.z; As[lc + 3][lr] = av.w;
        Bs[lc + 0][lr] = bv.x; Bs[lc + 1][lr] = bv.y;
        Bs[lc + 2][lr] = bv.z; Bs[lc + 3][lr] = bv.w;
        __syncthreads();
#pragma unroll
        for (int kk = 0; kk < 16; ++kk) {
            float4 a = *(const float4*)&As[kk][ty * 4];
            float4 b = *(const float4*)&Bs[kk][tx * 4];
            float aa[4] = {a.x, a.y, a.z, a.w};
            float bb[4] = {b.x, b.y, b.z, b.w};
#pragma unroll
            for (int i = 0; i < 4; ++i)
#pragma unroll
                for (int j = 0; j < 4; ++j) acc[i][j] += aa[i] * bb[j];
        }
    }

    // Write to per-head layout (B,H,S,DK). Tile is 64 wide = exactly one head.
    const int h = n0 >> 6;
#pragma unroll
    for (int i = 0; i < 4; ++i) {
        const int m = m0 + ty * 4 + i;
        const int b = m >> 11, s = m & (SS - 1);
        float* dst = O + (((size_t)b * NHEADS + h) * SS + s) * DKH + tx * 4;
        float4 v4 = make_float4(acc[i][0], acc[i][1], acc[i][2], acc[i][3]);
        *(float4*)dst = v4;
    }
}

// ---------------------------------------------------------------------------
// K2a: raw (pre-softmax) scores for lower-triangular tiles only.
// scores[i][j] = 0.125 * sum_dk q[i,dk]*k[j,dk], written into the
// attn_weights region of d_out (softmax kernel normalizes in place).
// ---------------------------------------------------------------------------
__global__ __launch_bounds__(256)
void k_scores(const float* __restrict__ qb, const float* __restrict__ kb,
              float* __restrict__ attn)
{
    const int kt = blockIdx.x;   // j tile
    const int qt = blockIdx.y;   // i tile
    const int bh = blockIdx.z;
    if (kt > qt) return;         // causal: skip strictly-upper tiles

    const int i0 = qt * 64, j0 = kt * 64;
    const float* __restrict__ qp = qb + (size_t)bh * SS * DKH;
    const float* __restrict__ kp = kb + (size_t)bh * SS * DKH;

    __shared__ float Qs[64][68];   // [dk][i]  (dk-major for float4 frag reads)
    __shared__ float Ks[64][68];   // [dk][j]

    const int tx = threadIdx.x, ty = threadIdx.y;
    const int tid = ty * 16 + tx;
    const int r  = tid >> 2;        // row within tile
    const int c0 = (tid & 3) * 16;  // dk chunk

    {
        const float4* qsrc = (const float4*)(qp + (size_t)(i0 + r) * DKH + c0);
        const float4* ksrc = (const float4*)(kp + (size_t)(j0 + r) * DKH + c0);
#pragma unroll
        for (int c = 0; c < 4; ++c) {
            float4 a = qsrc[c];
            Qs[c0 + c * 4 + 0][r] = a.x; Qs[c0 + c * 4 + 1][r] = a.y;
            Qs[c0 + c * 4 + 2][r] = a.z; Qs[c0 + c * 4 + 3][r] = a.w;
            float4 b = ksrc[c];
            Ks[c0 + c * 4 + 0][r] = b.x; Ks[c0 + c * 4 + 1][r] = b.y;
            Ks[c0 + c * 4 + 2][r] = b.z; Ks[c0 + c * 4 + 3][r] = b.w;
        }
    }
    __syncthreads();

    float acc[4][4] = {};
#pragma unroll
    for (int dk = 0; dk < 64; ++dk) {
        float4 a = *(const float4*)&Qs[dk][ty * 4];
        float4 b = *(const float4*)&Ks[dk][tx * 4];
        float aa[4] = {a.x, a.y, a.z, a.w};
        float bb[4] = {b.x, b.y, b.z, b.w};
#pragma unroll
        for (int i = 0; i < 4; ++i)
#pragma unroll
            for (int j = 0; j < 4; ++j) acc[i][j] += aa[i] * bb[j];
    }

    const float scale = 0.125f;  // 1/sqrt(64)
#pragma unroll
    for (int i = 0; i < 4; ++i) {
        const int gi = i0 + ty * 4 + i;
        float* dst = attn + ((size_t)bh * SS + gi) * SS + j0 + tx * 4;
        float4 v4 = make_float4(acc[i][0] * scale, acc[i][1] * scale,
                                acc[i][2] * scale, acc[i][3] * scale);
        *(float4*)dst = v4;
    }
}

// ---------------------------------------------------------------------------
// K2b: in-place causal softmax per row. Row fits in LDS (<= 8 KB).
// Writes exact 0.0f for masked (j > i) positions.
// ---------------------------------------------------------------------------
__global__ __launch_bounds__(256)
void k_softmax(float* __restrict__ attn)
{
    const int row = blockIdx.x;          // 0 .. B*H*S-1
    const int i   = row & (SS - 1);      // position within sequence
    float* p = attn + (size_t)row * SS;
    const int n = i + 1;                 // valid prefix length
    const int tid = threadIdx.x;

    __shared__ float buf[SS];
    __shared__ float red[4];

    float lmax = -1e30f;
    for (int j = tid; j < n; j += 256) {
        float x = p[j];
        buf[j] = x;
        lmax = fmaxf(lmax, x);
    }
#pragma unroll
    for (int o = 32; o; o >>= 1) lmax = fmaxf(lmax, __shfl_down(lmax, o));
    if ((tid & 63) == 0) red[tid >> 6] = lmax;
    __syncthreads();
    const float m = fmaxf(fmaxf(red[0], red[1]), fmaxf(red[2], red[3]));

    float lsum = 0.f;
    for (int j = tid; j < n; j += 256) {
        float e = __expf(buf[j] - m);
        buf[j] = e;
        lsum += e;
    }
#pragma unroll
    for (int o = 32; o; o >>= 1) lsum += __shfl_down(lsum, o);
    __syncthreads();                       // protect red[] reuse
    if ((tid & 63) == 0) red[tid >> 6] = lsum;
    __syncthreads();
    const float inv = 1.0f / (red[0] + red[1] + red[2] + red[3]);

    for (int j = tid; j < n; j += 256) p[j] = buf[j] * inv;
    for (int j = n + tid; j < SS; j += 256) p[j] = 0.0f;  // masked -> exact 0
}

// ---------------------------------------------------------------------------
// K3: PV.  attn_out[i,dk] = sum_{j<=i} attn[i,j] * v[j,dk]   (per b,h)
// Causal: k-loop only up to the diagonal tile (upper entries are 0 anyway).
// Writes into qb (q projection no longer needed).
// ---------------------------------------------------------------------------
__global__ __launch_bounds__(256)
void k_pv(const float* __restrict__ attn, const float* __restrict__ vb,
          float* __restrict__ ob)
{
    const int qt = blockIdx.x;   // i tile 0..31
    const int bh = blockIdx.y;
    const int i0 = qt * 64;
    const float* __restrict__ ap = attn + (size_t)bh * SS * SS;
    const float* __restrict__ vp = vb   + (size_t)bh * SS * DKH;

    __shared__ float Ps[64][68];  // [j_local][i_local]  (transposed)
    __shared__ float Vs[64][68];  // [j_local][dk]

    const int tx = threadIdx.x, ty = threadIdx.y;
    const int tid = ty * 16 + tx;
    const int r  = tid >> 2;
    const int c0 = (tid & 3) * 16;

    float acc[4][4] = {};

    for (int j0 = 0; j0 <= i0; j0 += 64) {
        __syncthreads();
        const float4* psrc = (const float4*)(ap + (size_t)(i0 + r) * SS + j0 + c0);
#pragma unroll
        for (int c = 0; c < 4; ++c) {
            float4 a = psrc[c];
            Ps[c0 + c * 4 + 0][r] = a.x; Ps[c0 + c * 4 + 1][r] = a.y;
            Ps[c0 + c * 4 + 2][r] = a.z; Ps[c0 + c * 4 + 3][r] = a.w;
        }
        const float4* vsrc = (const float4*)(vp + (size_t)(j0 + r) * DKH + c0);
        float4* vdst = (float4*)&Vs[r][c0];
#pragma unroll
        for (int c = 0; c < 4; ++c) vdst[c] = vsrc[c];
        __syncthreads();

#pragma unroll
        for (int jj = 0; jj < 64; ++jj) {
            float4 a = *(const float4*)&Ps[jj][ty * 4];
            float4 b = *(const float4*)&Vs[jj][tx * 4];
            float aa[4] = {a.x, a.y, a.z, a.w};
            float bb[4] = {b.x, b.y, b.z, b.w};
#pragma unroll
            for (int i = 0; i < 4; ++i)
#pragma unroll
                for (int j = 0; j < 4; ++j) acc[i][j] += aa[i] * bb[j];
        }
    }

#pragma unroll
    for (int i = 0; i < 4; ++i) {
        float* dst = ob + ((size_t)bh * SS + i0 + ty * 4 + i) * DKH + tx * 4;
        *(float4*)dst = make_float4(acc[i][0], acc[i][1], acc[i][2], acc[i][3]);
    }
}

// ---------------------------------------------------------------------------
// K4a: output projection + residual.
// pre[m,n] = sum_k ctx[m,k]*WO[n,k] + resid[m,n]
// ctx is read from the (B,H,S,DK) attn_out layout.
// ---------------------------------------------------------------------------
__global__ __launch_bounds__(256)
void k_out_proj(const float* __restrict__ ctx, const float* __restrict__ WO,
                const float* __restrict__ resid, float* __restrict__ pre)
{
    const int n0 = blockIdx.x * 64;
    const int m0 = blockIdx.y * 64;
    const int tx = threadIdx.x, ty = threadIdx.y;
    const int tid = ty * 16 + tx;

    __shared__ float As[16][68];
    __shared__ float Bs[16][68];

    float acc[4][4] = {};

    const int lr = tid >> 2;
    const int lc = (tid & 3) * 4;
    const int m  = m0 + lr;
    const int b  = m >> 11, s = m & (SS - 1);

    for (int k0 = 0; k0 < D_MODEL; k0 += 16) {
        const int kg = k0 + lc;
        const int h = kg >> 6, kd = kg & 63;
        float4 av = *(const float4*)(ctx + (((size_t)b * NHEADS + h) * SS + s) * DKH + kd);
        float4 bv = *(const float4*)(WO + (size_t)(n0 + lr) * D_MODEL + kg);
        __syncthreads();
        As[lc + 0][lr] = av.x; As[lc + 1][lr] = av.y;
        As[lc + 2][lr] = av.z; As[lc + 3][lr] = av.w;
        Bs[lc + 0][lr] = bv.x; Bs[lc + 1][lr] = bv.y;
        Bs[lc + 2][lr] = bv.z; Bs[lc + 3][lr] = bv.w;
        __syncthreads();
#pragma unroll
        for (int kk = 0; kk < 16; ++kk) {
            float4 a = *(const float4*)&As[kk][ty * 4];
            float4 b4 = *(const float4*)&Bs[kk][tx * 4];
            float aa[4] = {a.x, a.y, a.z, a.w};
            float bb[4] = {b4.x, b4.y, b4.z, b4.w};
#pragma unroll
            for (int i = 0; i < 4; ++i)
#pragma unroll
                for (int j = 0; j < 4; ++j) acc[i][j] += aa[i] * bb[j];
        }
    }

#pragma unroll
    for (int i = 0; i < 4; ++i) {
        const int mm = m0 + ty * 4 + i;
        const float4 r4 = *(const float4*)(resid + (size_t)mm * D_MODEL + n0 + tx * 4);
        float4 v4 = make_float4(acc[i][0] + r4.x, acc[i][1] + r4.y,
                                acc[i][2] + r4.z, acc[i][3] + r4.w);
        *(float4*)(pre + (size_t)mm * D_MODEL + n0 + tx * 4) = v4;
    }
}

// ---------------------------------------------------------------------------
// K4b: LayerNorm per row of 1024.
// ---------------------------------------------------------------------------
__global__ __launch_bounds__(256)
void k_ln(const float* __restrict__ pre, const float* __restrict__ gamma,
          const float* __restrict__ beta, float* __restrict__ out)
{
    const int row = blockIdx.x;
    const int tid = threadIdx.x;
    const float* p = pre + (size_t)row * D_MODEL;
    float* o = out + (size_t)row * D_MODEL;

    __shared__ float red[4];

    float4 x = ((const float4*)p)[tid];
    float s = x.x + x.y + x.z + x.w;
#pragma unroll
    for (int off = 32; off; off >>= 1) s += __shfl_down(s, off);
    if ((tid & 63) == 0) red[tid >> 6] = s;
    __syncthreads();
    const float mu = (red[0] + red[1] + red[2] + red[3]) * (1.0f / D_MODEL);

    float dx[4] = {x.x - mu, x.y - mu, x.z - mu, x.w - mu};
    float ss = dx[0] * dx[0] + dx[1] * dx[1] + dx[2] * dx[2] + dx[3] * dx[3];
#pragma unroll
    for (int off = 32; off; off >>= 1) ss += __shfl_down(ss, off);
    __syncthreads();                      // protect red[] reuse
    if ((tid & 63) == 0) red[tid >> 6] = ss;
    __syncthreads();
    const float var = (red[0] + red[1] + red[2] + red[3]) * (1.0f / D_MODEL);
    const float inv = rsqrtf(var + 1e-5f);

    float4 g = ((const float4*)gamma)[tid];
    float4 be = ((const float4*)beta)[tid];
    float4 y = make_float4(dx[0] * inv * g.x + be.x, dx[1] * inv * g.y + be.y,
                           dx[2] * inv * g.z + be.z, dx[3] * inv * g.w + be.w);
    ((float4*)o)[tid] = y;
}

// ---------------------------------------------------------------------------
extern "C" void kernel_launch(void* const* d_in, const int* in_sizes, int n_in,
                              void* d_out, int out_size, void* d_ws, size_t ws_size,
                              hipStream_t stream)
{
    const float* Q     = (const float*)d_in[0];
    const float* K     = (const float*)d_in[1];
    const float* V     = (const float*)d_in[2];
    // d_in[3] = causal mask, known structure (tril) -> unused
    const float* WQ    = (const float*)d_in[4];
    const float* WK    = (const float*)d_in[5];
    const float* WV    = (const float*)d_in[6];
    const float* WO    = (const float*)d_in[7];
    const float* gamma = (const float*)d_in[8];
    const float* beta  = (const float*)d_in[9];

    float* out  = (float*)d_out;                       // (B,S,D)   4.19M floats
    float* attn = out + (size_t)BB * SS * D_MODEL;     // (B,H,S,S) 134.2M floats

    // workspace: 3 x 16.8 MB (q/k/v projections). attn_out reuses qb,
    // pre-LN buffer reuses kb.  Total 50.3 MB.
    float* qb = (float*)d_ws;
    float* kb = qb + (size_t)MM * D_MODEL;
    float* vb = kb + (size_t)MM * D_MODEL;

    k_qkv_proj<<<dim3(16, 64, 3), dim3(16, 16), 0, stream>>>(Q, K, V, WQ, WK, WV,
                                                             qb, kb, vb);
    k_scores<<<dim3(32, 32, BB * NHEADS), dim3(16, 16), 0, stream>>>(qb, kb, attn);
    k_softmax<<<dim3(BB * NHEADS * SS), dim3(256), 0, stream>>>(attn);
    k_pv<<<dim3(32, BB * NHEADS), dim3(16, 16), 0, stream>>>(attn, vb, qb);
    k_out_proj<<<dim3(16, 64), dim3(16, 16), 0, stream>>>(qb, WO, Q, kb);
    k_ln<<<dim3(MM), dim3(256), 0, stream>>>(kb, gamma, beta, out);
}

// Round 2
// 890.115 us; speedup vs baseline: 1.7771x; 1.7771x over previous
//
#include <hip/hip_runtime.h>
#include <cstdint>
#include <cstddef>

#define D_MODEL 1024
#define NHEADS  16
#define DKH     64
#define BB      2
#define SS      2048
#define MM      (BB*SS)

typedef short bf16x8 __attribute__((ext_vector_type(8)));
typedef float f32x4  __attribute__((ext_vector_type(4)));

#define MFMA(a,b,c) __builtin_amdgcn_mfma_f32_16x16x32_bf16(a,b,c,0,0,0)

__device__ __forceinline__ unsigned short f2bf(float f) {
    unsigned int u = __float_as_uint(f);
    u += 0x7FFFu + ((u >> 16) & 1u);          // RNE
    return (unsigned short)(u >> 16);
}

__device__ __forceinline__ void gld16(const unsigned short* g, char* l) {
    __builtin_amdgcn_global_load_lds((const __attribute__((address_space(1))) void*)g,
                                     (__attribute__((address_space(3))) void*)l, 16, 0, 0);
}

// Stage a tile with 128-byte rows into LDS via global_load_lds, with the
// st-8-row XOR swizzle applied on the GLOBAL source side (rule #21: linear
// LDS dest + inverse-swizzled source + swizzled reads).
// NISS issues of 4096 B; gstride in bf16 elements.
template<int NISS>
__device__ __forceinline__ void stage128(char* ldsbase, const unsigned short* gorig,
                                         long gstride, int w, int l) {
#pragma unroll
    for (int is = 0; is < NISS; ++is) {
        const int pb = is * 4096 + w * 1024 + l * 16;        // phys byte my 16B lands at
        const int lb = pb ^ (((pb >> 7) & 7) << 4);          // logical source offset
        gld16(gorig + (long)(lb >> 7) * gstride + ((lb & 127) >> 1),
              ldsbase + is * 4096 + w * 1024);               // wave-uniform dest base
    }
}

// Swizzled fragment read: row-major tile with 128B rows; returns 8 bf16.
__device__ __forceinline__ bf16x8 fld(const char* lds, int row, int kb) {
    int lofs = row * 128 + kb;
    lofs ^= ((row & 7) << 4);
    return *(const bf16x8*)(lds + lofs);
}

// ---------------------------------------------------------------------------
// fp32 -> bf16 conversion of Q,K,V,WQ,WK,WV,WO into one contiguous ws region.
// 16,777,216 elements total; 8 per thread.
// ---------------------------------------------------------------------------
__global__ __launch_bounds__(256)
void k_cvt(const float* __restrict__ Q, const float* __restrict__ K,
           const float* __restrict__ V, const float* __restrict__ WQ,
           const float* __restrict__ WK, const float* __restrict__ WV,
           const float* __restrict__ WO, unsigned short* __restrict__ dst)
{
    const size_t i8 = ((size_t)blockIdx.x * 256 + threadIdx.x) * 8;
    const size_t C = 4194304;
    const float* src; size_t off;
    if (i8 < C)          { src = Q; off = i8; }
    else if (i8 < 2 * C) { src = K; off = i8 - C; }
    else if (i8 < 3 * C) { src = V; off = i8 - 2 * C; }
    else {
        const size_t t = i8 - 3 * C;
        const size_t wi = t >> 20;
        off = t & 1048575;
        src = (wi == 0) ? WQ : (wi == 1) ? WK : (wi == 2) ? WV : WO;
    }
    const float4 f0 = ((const float4*)(src + off))[0];
    const float4 f1 = ((const float4*)(src + off))[1];
    bf16x8 v;
    v[0] = (short)f2bf(f0.x); v[1] = (short)f2bf(f0.y);
    v[2] = (short)f2bf(f0.z); v[3] = (short)f2bf(f0.w);
    v[4] = (short)f2bf(f1.x); v[5] = (short)f2bf(f1.y);
    v[6] = (short)f2bf(f1.z); v[7] = (short)f2bf(f1.w);
    *(bf16x8*)(dst + i8) = v;
}

// ---------------------------------------------------------------------------
// bf16 MFMA GEMM-NT: A (4096 x 1024 row-major), B (1024 x 1024 row-major,
// i.e. N x K), 128x128 tile, BK=64, 4 waves each owning a 64x64 sub-tile.
// MODE 0: C -> per-head bf16 (b,h,s,dk)        (q,k projections)
// MODE 1: C -> per-head transposed bf16 (b,h,dk,s)  (v projection)
// MODE 2: C -> fp32 rowmajor + residual        (output projection)
// ---------------------------------------------------------------------------
template<int MODE>
__global__ __launch_bounds__(256)
void k_gemm(const unsigned short* __restrict__ A, const unsigned short* __restrict__ B,
            unsigned short* __restrict__ obf, const float* __restrict__ resid,
            float* __restrict__ ofp)
{
    __shared__ char lds[32768];            // A tile 16K | B tile 16K
    const int tid = threadIdx.x;
    const int w = tid >> 6, l = tid & 63;
    const int n0 = blockIdx.x * 128, m0 = blockIdx.y * 128;
    const int wr = (w >> 1) * 64, wc = (w & 1) * 64;

    f32x4 acc[4][4] = {};

    for (int kt = 0; kt < 16; ++kt) {
        __syncthreads();
        stage128<4>(lds,         A + (size_t)m0 * 1024 + kt * 64, 1024, w, l);
        stage128<4>(lds + 16384, B + (size_t)n0 * 1024 + kt * 64, 1024, w, l);
        __syncthreads();
#pragma unroll
        for (int ks = 0; ks < 2; ++ks) {
            const int kb = ks * 64 + (l >> 4) * 16;
            bf16x8 av[4], bv[4];
#pragma unroll
            for (int i = 0; i < 4; ++i) av[i] = fld(lds,         wr + i * 16 + (l & 15), kb);
#pragma unroll
            for (int j = 0; j < 4; ++j) bv[j] = fld(lds + 16384, wc + j * 16 + (l & 15), kb);
#pragma unroll
            for (int i = 0; i < 4; ++i)
#pragma unroll
                for (int j = 0; j < 4; ++j)
                    acc[i][j] = MFMA(av[i], bv[j], acc[i][j]);
        }
    }

#pragma unroll
    for (int i = 0; i < 4; ++i)
#pragma unroll
        for (int j = 0; j < 4; ++j)
#pragma unroll
            for (int r = 0; r < 4; ++r) {
                const int m = m0 + wr + i * 16 + ((l >> 4) << 2) + r;
                const int n = n0 + wc + j * 16 + (l & 15);
                const float v = acc[i][j][r];
                if (MODE == 0) {
                    const int b = m >> 11, s = m & 2047, h = n >> 6, dk = n & 63;
                    obf[((size_t)(b * 16 + h) * 2048 + s) * 64 + dk] = f2bf(v);
                } else if (MODE == 1) {
                    const int b = m >> 11, s = m & 2047, h = n >> 6, dk = n & 63;
                    obf[((size_t)(b * 16 + h) * 64 + dk) * 2048 + s] = f2bf(v);
                } else {
                    const size_t o = (size_t)m * 1024 + n;
                    ofp[o] = v + resid[o];
                }
            }
}

// ---------------------------------------------------------------------------
// Fused scores + causal softmax (flash 2-pass recompute).
// Block = (qt, bh): 64 q-rows; 4 waves x 16 rows. Writes attn fp32 (full rows
// incl. zeros) to d_out and P bf16 (lower-triangular tiles) to ws.
// ---------------------------------------------------------------------------
__global__ __launch_bounds__(256)
void k_attn(const unsigned short* __restrict__ Qh, const unsigned short* __restrict__ Kh,
            float* __restrict__ attn, unsigned short* __restrict__ P)
{
    __shared__ char Qs[8192];
    __shared__ char Ks[8192];
    const int tid = threadIdx.x, w = tid >> 6, l = tid & 63;
    const int qt = blockIdx.x, bh = blockIdx.y;
    const int i0 = qt * 64;
    const unsigned short* qb = Qh + (size_t)bh * SS * DKH;
    const unsigned short* kb = Kh + (size_t)bh * SS * DKH;
    float*          ab = attn + (size_t)bh * SS * SS;
    unsigned short* pb = P    + (size_t)bh * SS * SS;

    stage128<2>(Qs, qb + (size_t)i0 * DKH, DKH, w, l);
    __syncthreads();
    bf16x8 qa[2];
#pragma unroll
    for (int ks = 0; ks < 2; ++ks)
        qa[ks] = fld(Qs, w * 16 + (l & 15), ks * 64 + (l >> 4) * 16);

    float m4[4], l4[4];
#pragma unroll
    for (int r = 0; r < 4; ++r) { m4[r] = -3.0e38f; l4[r] = 0.f; }

    const int qrow = i0 + w * 16 + ((l >> 4) << 2);   // + r

    // ---- pass 1: online m, l ----
    for (int kt = 0; kt <= qt; ++kt) {
        __syncthreads();
        stage128<2>(Ks, kb + (size_t)kt * 64 * DKH, DKH, w, l);
        __syncthreads();
        f32x4 sc[4] = {};
#pragma unroll
        for (int ks = 0; ks < 2; ++ks) {
            const int kbyt = ks * 64 + (l >> 4) * 16;
#pragma unroll
            for (int n = 0; n < 4; ++n) {
                bf16x8 bv = fld(Ks, n * 16 + (l & 15), kbyt);
                sc[n] = MFMA(qa[ks], bv, sc[n]);
            }
        }
#pragma unroll
        for (int n = 0; n < 4; ++n) {
            const int kp = kt * 64 + n * 16 + (l & 15);
#pragma unroll
            for (int r = 0; r < 4; ++r) {
                float s = sc[n][r] * 0.125f;
                if (kt == qt && kp > qrow + r) s = -3.0e38f;
                sc[n][r] = s;
            }
        }
        float tm[4], ts[4];
#pragma unroll
        for (int r = 0; r < 4; ++r)
            tm[r] = fmaxf(fmaxf(sc[0][r], sc[1][r]), fmaxf(sc[2][r], sc[3][r]));
#pragma unroll
        for (int off = 1; off < 16; off <<= 1)
#pragma unroll
            for (int r = 0; r < 4; ++r) tm[r] = fmaxf(tm[r], __shfl_xor(tm[r], off));
#pragma unroll
        for (int r = 0; r < 4; ++r) {
            const float mn = fmaxf(m4[r], tm[r]);
            const float e0 = __expf(sc[0][r] - mn), e1 = __expf(sc[1][r] - mn);
            const float e2 = __expf(sc[2][r] - mn), e3 = __expf(sc[3][r] - mn);
            ts[r] = (e0 + e1) + (e2 + e3);
            l4[r] *= __expf(m4[r] - mn);
            m4[r] = mn;
        }
#pragma unroll
        for (int off = 1; off < 16; off <<= 1)
#pragma unroll
            for (int r = 0; r < 4; ++r) ts[r] += __shfl_xor(ts[r], off);
#pragma unroll
        for (int r = 0; r < 4; ++r) l4[r] += ts[r];
    }

    float inv[4];
#pragma unroll
    for (int r = 0; r < 4; ++r) inv[r] = 1.0f / l4[r];

    // ---- pass 2: recompute, normalize, write attn fp32 + P bf16 ----
    for (int kt = 0; kt <= qt; ++kt) {
        __syncthreads();
        stage128<2>(Ks, kb + (size_t)kt * 64 * DKH, DKH, w, l);
        __syncthreads();
        f32x4 sc[4] = {};
#pragma unroll
        for (int ks = 0; ks < 2; ++ks) {
            const int kbyt = ks * 64 + (l >> 4) * 16;
#pragma unroll
            for (int n = 0; n < 4; ++n) {
                bf16x8 bv = fld(Ks, n * 16 + (l & 15), kbyt);
                sc[n] = MFMA(qa[ks], bv, sc[n]);
            }
        }
#pragma unroll
        for (int n = 0; n < 4; ++n) {
            const int kp = kt * 64 + n * 16 + (l & 15);
#pragma unroll
            for (int r = 0; r < 4; ++r) {
                float s = sc[n][r] * 0.125f;
                if (kt == qt && kp > qrow + r) s = -3.0e38f;
                const float wgt = __expf(s - m4[r]) * inv[r];   // masked -> exact 0
                ab[(size_t)(qrow + r) * SS + kp] = wgt;
                pb[(size_t)(qrow + r) * SS + kp] = f2bf(wgt);
            }
        }
    }

    // ---- zero-fill causal upper region (cols >= (qt+1)*64) ----
    const int zs = (qt + 1) * 64;
    if (zs < SS) {
        const int rl = tid >> 2;
        float4* row = (float4*)(ab + (size_t)(i0 + rl) * SS);
        for (int c = (zs >> 2) + (tid & 3); c < SS / 4; c += 4)
            row[c] = make_float4(0.f, 0.f, 0.f, 0.f);
    }
}

// ---------------------------------------------------------------------------
// PV: O[q][dk] = sum_{kp<=q} P[q][kp] * V[kp][dk] per (b,h). BM=64 (aligned
// with attn blocks so every read P tile was written), BN=64, BK=64.
// Output -> ctx bf16 row-major (b*S+s, h*64+dk).
// ---------------------------------------------------------------------------
__global__ __launch_bounds__(256)
void k_pv(const unsigned short* __restrict__ P, const unsigned short* __restrict__ VT,
          unsigned short* __restrict__ ctx)
{
    __shared__ char Ps[8192];
    __shared__ char Vs[8192];
    const int tid = threadIdx.x, w = tid >> 6, l = tid & 63;
    const int qt = blockIdx.x, bh = blockIdx.y;
    const int i0 = qt * 64;
    const unsigned short* pbase = P  + (size_t)bh * SS * SS + (size_t)i0 * SS;
    const unsigned short* vbase = VT + (size_t)bh * DKH * SS;

    f32x4 acc[4] = {};
    for (int kt = 0; kt <= qt; ++kt) {
        __syncthreads();
        stage128<2>(Ps, pbase + kt * 64, SS, w, l);
        stage128<2>(Vs, vbase + kt * 64, SS, w, l);
        __syncthreads();
#pragma unroll
        for (int ks = 0; ks < 2; ++ks) {
            const int kbyt = ks * 64 + (l >> 4) * 16;
            const bf16x8 a = fld(Ps, w * 16 + (l & 15), kbyt);
#pragma unroll
            for (int n = 0; n < 4; ++n) {
                const bf16x8 b = fld(Vs, n * 16 + (l & 15), kbyt);
                acc[n] = MFMA(a, b, acc[n]);
            }
        }
    }
    const int b = bh >> 4, h = bh & 15;
    const int qrow = i0 + w * 16 + ((l >> 4) << 2);
#pragma unroll
    for (int n = 0; n < 4; ++n)
#pragma unroll
        for (int r = 0; r < 4; ++r) {
            const int dk = n * 16 + (l & 15);
            ctx[(size_t)(b * SS + qrow + r) * D_MODEL + h * DKH + dk] = f2bf(acc[n][r]);
        }
}

// ---------------------------------------------------------------------------
// LayerNorm per row of 1024 (fp32 in, fp32 out).
// ---------------------------------------------------------------------------
__global__ __launch_bounds__(256)
void k_ln(const float* __restrict__ pre, const float* __restrict__ gamma,
          const float* __restrict__ beta, float* __restrict__ out)
{
    const int row = blockIdx.x;
    const int tid = threadIdx.x;
    const float* p = pre + (size_t)row * D_MODEL;
    float* o = out + (size_t)row * D_MODEL;

    __shared__ float red[4];

    float4 x = ((const float4*)p)[tid];
    float s = x.x + x.y + x.z + x.w;
#pragma unroll
    for (int off = 32; off; off >>= 1) s += __shfl_down(s, off);
    if ((tid & 63) == 0) red[tid >> 6] = s;
    __syncthreads();
    const float mu = (red[0] + red[1] + red[2] + red[3]) * (1.0f / D_MODEL);

    float dx[4] = {x.x - mu, x.y - mu, x.z - mu, x.w - mu};
    float ss = dx[0] * dx[0] + dx[1] * dx[1] + dx[2] * dx[2] + dx[3] * dx[3];
#pragma unroll
    for (int off = 32; off; off >>= 1) ss += __shfl_down(ss, off);
    __syncthreads();
    if ((tid & 63) == 0) red[tid >> 6] = ss;
    __syncthreads();
    const float var = (red[0] + red[1] + red[2] + red[3]) * (1.0f / D_MODEL);
    const float inv = rsqrtf(var + 1e-5f);

    const float4 g  = ((const float4*)gamma)[tid];
    const float4 be = ((const float4*)beta)[tid];
    ((float4*)o)[tid] = make_float4(dx[0] * inv * g.x + be.x, dx[1] * inv * g.y + be.y,
                                    dx[2] * inv * g.z + be.z, dx[3] * inv * g.w + be.w);
}

// ---------------------------------------------------------------------------
extern "C" void kernel_launch(void* const* d_in, const int* in_sizes, int n_in,
                              void* d_out, int out_size, void* d_ws, size_t ws_size,
                              hipStream_t stream)
{
    const float* Q     = (const float*)d_in[0];
    const float* K     = (const float*)d_in[1];
    const float* V     = (const float*)d_in[2];
    // d_in[3] = causal mask (known tril) -> unused
    const float* WQ    = (const float*)d_in[4];
    const float* WK    = (const float*)d_in[5];
    const float* WV    = (const float*)d_in[6];
    const float* WO    = (const float*)d_in[7];
    const float* gamma = (const float*)d_in[8];
    const float* beta  = (const float*)d_in[9];

    float* out  = (float*)d_out;                       // (B,S,D)
    float* attn = out + (size_t)BB * SS * D_MODEL;     // (B,H,S,S) fp32

    // ws layout (bytes):
    //   [0,   32M)  bf16 conversions: Xq,Xk,Xv (4M elems each) | Wq,Wk,Wv,Wo (1M each)
    //   [32M, 56M)  Qh, Kh (b,h,s,dk) | VhT (b,h,dk,s) bf16, 8 MiB each
    //   [56M, 312M) P bf16 (b,h,q,k)
    //   [312M,320M) ctx bf16 (m,1024)
    //   [320M,336M) preLN fp32
    char* ws = (char*)d_ws;
    unsigned short* cvt = (unsigned short*)ws;
    unsigned short* Xq = cvt;
    unsigned short* Xk = cvt + 4194304;
    unsigned short* Xv = cvt + 2 * 4194304;
    unsigned short* Wq = cvt + 3 * 4194304;
    unsigned short* Wk = Wq + 1048576;
    unsigned short* Wv = Wk + 1048576;
    unsigned short* Wo = Wv + 1048576;
    unsigned short* Qh  = (unsigned short*)(ws + 33554432);
    unsigned short* Kh  = Qh + 4194304;
    unsigned short* VhT = Kh + 4194304;
    unsigned short* Pb  = (unsigned short*)(ws + 58720256);
    unsigned short* ctx = (unsigned short*)(ws + 58720256 + 268435456);
    float*          pre = (float*)(ws + 58720256 + 268435456 + 8388608);

    k_cvt<<<dim3(8192), dim3(256), 0, stream>>>(Q, K, V, WQ, WK, WV, WO, cvt);
    k_gemm<0><<<dim3(8, 32), dim3(256), 0, stream>>>(Xq, Wq, Qh, nullptr, nullptr);
    k_gemm<0><<<dim3(8, 32), dim3(256), 0, stream>>>(Xk, Wk, Kh, nullptr, nullptr);
    k_gemm<1><<<dim3(8, 32), dim3(256), 0, stream>>>(Xv, Wv, VhT, nullptr, nullptr);
    k_attn<<<dim3(32, 32), dim3(256), 0, stream>>>(Qh, Kh, attn, Pb);
    k_pv<<<dim3(32, 32), dim3(256), 0, stream>>>(Pb, VhT, ctx);
    k_gemm<2><<<dim3(8, 32), dim3(256), 0, stream>>>(ctx, Wo, nullptr, Q, pre);
    k_ln<<<dim3(MM), dim3(256), 0, stream>>>(pre, gamma, beta, out);
}

// Round 3
// 844.551 us; speedup vs baseline: 1.8729x; 1.0540x over previous
//
#include <hip/hip_runtime.h>
#include <cstdint>
#include <cstddef>

#define D_MODEL 1024
#define NHEADS  16
#define DKH     64
#define BB      2
#define SS      2048
#define MM      (BB*SS)

typedef short bf16x8 __attribute__((ext_vector_type(8)));
typedef short bf16x4 __attribute__((ext_vector_type(4)));
typedef float f32x4  __attribute__((ext_vector_type(4)));

#define MFMA(a,b,c) __builtin_amdgcn_mfma_f32_16x16x32_bf16(a,b,c,0,0,0)

__device__ __forceinline__ unsigned short f2bf(float f) {
    unsigned int u = __float_as_uint(f);
    u += 0x7FFFu + ((u >> 16) & 1u);          // RNE
    return (unsigned short)(u >> 16);
}
__device__ __forceinline__ float bf2f(unsigned short u) {
    return __uint_as_float(((unsigned int)u) << 16);
}

__device__ __forceinline__ void gld16(const unsigned short* g, char* l) {
    __builtin_amdgcn_global_load_lds((const __attribute__((address_space(1))) void*)g,
                                     (__attribute__((address_space(3))) void*)l, 16, 0, 0);
}

// Stage a tile with 128-byte rows into LDS via global_load_lds; st-8-row XOR
// swizzle applied on the GLOBAL source side (rule #21: linear LDS dest +
// inverse-swizzled source + swizzled reads). NISS issues of 4096 B.
template<int NISS>
__device__ __forceinline__ void stage128(char* ldsbase, const unsigned short* gorig,
                                         long gstride, int w, int l) {
#pragma unroll
    for (int is = 0; is < NISS; ++is) {
        const int pb = is * 4096 + w * 1024 + l * 16;        // phys byte of my 16B
        const int lb = pb ^ (((pb >> 7) & 7) << 4);          // logical source offset
        gld16(gorig + (long)(lb >> 7) * gstride + ((lb & 127) >> 1),
              ldsbase + is * 4096 + w * 1024);               // wave-uniform dest base
    }
}

// Swizzled fragment read: row-major tile with 128B rows; returns 8 bf16.
__device__ __forceinline__ bf16x8 fld(const char* lds, int row, int kb) {
    int lofs = row * 128 + kb;
    lofs ^= ((row & 7) << 4);
    return *(const bf16x8*)(lds + lofs);
}

// ---------------------------------------------------------------------------
// fp32 -> bf16 conversion of Q,K,V,WQ,WK,WV,WO into one contiguous ws region.
// ---------------------------------------------------------------------------
__global__ __launch_bounds__(256)
void k_cvt(const float* __restrict__ Q, const float* __restrict__ K,
           const float* __restrict__ V, const float* __restrict__ WQ,
           const float* __restrict__ WK, const float* __restrict__ WV,
           const float* __restrict__ WO, unsigned short* __restrict__ dst)
{
    const size_t i8 = ((size_t)blockIdx.x * 256 + threadIdx.x) * 8;
    const size_t C = 4194304;
    const float* src; size_t off;
    if (i8 < C)          { src = Q; off = i8; }
    else if (i8 < 2 * C) { src = K; off = i8 - C; }
    else if (i8 < 3 * C) { src = V; off = i8 - 2 * C; }
    else {
        const size_t t = i8 - 3 * C;
        const size_t wi = t >> 20;
        off = t & 1048575;
        src = (wi == 0) ? WQ : (wi == 1) ? WK : (wi == 2) ? WV : WO;
    }
    const float4 f0 = ((const float4*)(src + off))[0];
    const float4 f1 = ((const float4*)(src + off))[1];
    bf16x8 v;
    v[0] = (short)f2bf(f0.x); v[1] = (short)f2bf(f0.y);
    v[2] = (short)f2bf(f0.z); v[3] = (short)f2bf(f0.w);
    v[4] = (short)f2bf(f1.x); v[5] = (short)f2bf(f1.y);
    v[6] = (short)f2bf(f1.z); v[7] = (short)f2bf(f1.w);
    *(bf16x8*)(dst + i8) = v;
}

// ---------------------------------------------------------------------------
// QKV projection GEMM-NT, z picks {Q,K,V}. 128x128 tile, BK=64, 4 waves.
// z=0,1: per-head (b,h,s,dk) bf16.  z=2: transposed per-head (b,h,dk,s).
// ---------------------------------------------------------------------------
__global__ __launch_bounds__(256)
void k_qkv(const unsigned short* __restrict__ Xq, const unsigned short* __restrict__ Xk,
           const unsigned short* __restrict__ Xv, const unsigned short* __restrict__ Wq,
           const unsigned short* __restrict__ Wk, const unsigned short* __restrict__ Wv,
           unsigned short* __restrict__ Qh, unsigned short* __restrict__ Kh,
           unsigned short* __restrict__ VhT)
{
    __shared__ char lds[32768];
    const int z = blockIdx.z;
    const unsigned short* __restrict__ A = (z == 0) ? Xq : (z == 1) ? Xk : Xv;
    const unsigned short* __restrict__ B = (z == 0) ? Wq : (z == 1) ? Wk : Wv;
    unsigned short* __restrict__ O       = (z == 0) ? Qh : (z == 1) ? Kh : VhT;

    const int tid = threadIdx.x;
    const int w = tid >> 6, l = tid & 63;
    const int n0 = blockIdx.x * 128, m0 = blockIdx.y * 128;
    const int wr = (w >> 1) * 64, wc = (w & 1) * 64;

    f32x4 acc[4][4] = {};

    for (int kt = 0; kt < 16; ++kt) {
        __syncthreads();
        stage128<4>(lds,         A + (size_t)m0 * 1024 + kt * 64, 1024, w, l);
        stage128<4>(lds + 16384, B + (size_t)n0 * 1024 + kt * 64, 1024, w, l);
        __syncthreads();
#pragma unroll
        for (int ks = 0; ks < 2; ++ks) {
            const int kb = ks * 64 + (l >> 4) * 16;
            bf16x8 av[4], bv[4];
#pragma unroll
            for (int i = 0; i < 4; ++i) av[i] = fld(lds,         wr + i * 16 + (l & 15), kb);
#pragma unroll
            for (int j = 0; j < 4; ++j) bv[j] = fld(lds + 16384, wc + j * 16 + (l & 15), kb);
#pragma unroll
            for (int i = 0; i < 4; ++i)
#pragma unroll
                for (int j = 0; j < 4; ++j)
                    acc[i][j] = MFMA(av[i], bv[j], acc[i][j]);
        }
    }

#pragma unroll
    for (int i = 0; i < 4; ++i)
#pragma unroll
        for (int j = 0; j < 4; ++j)
#pragma unroll
            for (int r = 0; r < 4; ++r) {
                const int m = m0 + wr + i * 16 + ((l >> 4) << 2) + r;
                const int n = n0 + wc + j * 16 + (l & 15);
                const int b = m >> 11, s = m & 2047, h = n >> 6, dk = n & 63;
                const unsigned short bv = f2bf(acc[i][j][r]);
                if (z < 2) O[((size_t)(b * 16 + h) * 2048 + s) * 64 + dk] = bv;
                else       O[((size_t)(b * 16 + h) * 64 + dk) * 2048 + s] = bv;
            }
}

// ---------------------------------------------------------------------------
// Fused attention: scores + causal softmax + attn-weight write + PV.
// Block = (qt, bh): 64 q-rows, 4 waves x 16 rows.
//   pass 1: online m,l (no stores)
//   pass 2: recompute, wgt=exp(s-m)/l, P-tile -> swizzled LDS (bf16),
//           PV MFMA from LDS, coalesced fp32 attn store from LDS.
// O (ctx) written coalesced via LDS transpose. Upper triangle zero-filled
// with row-contiguous float4 stores.
// ---------------------------------------------------------------------------
__global__ __launch_bounds__(256)
void k_attn(const unsigned short* __restrict__ Qh, const unsigned short* __restrict__ Kh,
            const unsigned short* __restrict__ VhT, float* __restrict__ attn,
            unsigned short* __restrict__ ctx)
{
    __shared__ char Qs[8192];
    __shared__ char Ks[8192];
    __shared__ char Vs[8192];
    __shared__ char Ps[8192];

    const int tid = threadIdx.x, w = tid >> 6, l = tid & 63;
    const int qt = blockIdx.x, bh = blockIdx.y;
    const int i0 = qt * 64;
    const unsigned short* qb = Qh  + (size_t)bh * SS * DKH;
    const unsigned short* kb = Kh  + (size_t)bh * SS * DKH;
    const unsigned short* vb = VhT + (size_t)bh * DKH * SS;
    float* ab = attn + (size_t)bh * SS * SS;

    stage128<2>(Qs, qb + (size_t)i0 * DKH, DKH, w, l);
    __syncthreads();
    bf16x8 qa[2];
#pragma unroll
    for (int ks = 0; ks < 2; ++ks)
        qa[ks] = fld(Qs, w * 16 + (l & 15), ks * 64 + (l >> 4) * 16);

    float m4[4], l4[4];
#pragma unroll
    for (int r = 0; r < 4; ++r) { m4[r] = -3.0e38f; l4[r] = 0.f; }

    const int qrow = i0 + w * 16 + ((l >> 4) << 2);   // + r

    // ---- pass 1: online m, l ----
    for (int kt = 0; kt <= qt; ++kt) {
        __syncthreads();
        stage128<2>(Ks, kb + (size_t)kt * 64 * DKH, DKH, w, l);
        __syncthreads();
        f32x4 sc[4] = {};
#pragma unroll
        for (int ks = 0; ks < 2; ++ks) {
            const int kbyt = ks * 64 + (l >> 4) * 16;
#pragma unroll
            for (int n = 0; n < 4; ++n)
                sc[n] = MFMA(qa[ks], fld(Ks, n * 16 + (l & 15), kbyt), sc[n]);
        }
#pragma unroll
        for (int n = 0; n < 4; ++n) {
            const int kp = kt * 64 + n * 16 + (l & 15);
#pragma unroll
            for (int r = 0; r < 4; ++r) {
                float s = sc[n][r] * 0.125f;
                if (kt == qt && kp > qrow + r) s = -3.0e38f;
                sc[n][r] = s;
            }
        }
        float tm[4], ts[4];
#pragma unroll
        for (int r = 0; r < 4; ++r)
            tm[r] = fmaxf(fmaxf(sc[0][r], sc[1][r]), fmaxf(sc[2][r], sc[3][r]));
#pragma unroll
        for (int off = 1; off < 16; off <<= 1)
#pragma unroll
            for (int r = 0; r < 4; ++r) tm[r] = fmaxf(tm[r], __shfl_xor(tm[r], off));
#pragma unroll
        for (int r = 0; r < 4; ++r) {
            const float mn = fmaxf(m4[r], tm[r]);
            const float e0 = __expf(sc[0][r] - mn), e1 = __expf(sc[1][r] - mn);
            const float e2 = __expf(sc[2][r] - mn), e3 = __expf(sc[3][r] - mn);
            ts[r] = (e0 + e1) + (e2 + e3);
            l4[r] *= __expf(m4[r] - mn);
            m4[r] = mn;
        }
#pragma unroll
        for (int off = 1; off < 16; off <<= 1)
#pragma unroll
            for (int r = 0; r < 4; ++r) ts[r] += __shfl_xor(ts[r], off);
#pragma unroll
        for (int r = 0; r < 4; ++r) l4[r] += ts[r];
    }

    float inv[4];
#pragma unroll
    for (int r = 0; r < 4; ++r) inv[r] = 1.0f / l4[r];

    f32x4 acc_o[4] = {};

    // ---- pass 2: recompute + write attn + PV ----
    for (int kt = 0; kt <= qt; ++kt) {
        __syncthreads();                               // prev-iter LDS readers done
        stage128<2>(Ks, kb + (size_t)kt * 64 * DKH, DKH, w, l);
        stage128<2>(Vs, vb + kt * 64, SS, w, l);
        __syncthreads();
        f32x4 sc[4] = {};
#pragma unroll
        for (int ks = 0; ks < 2; ++ks) {
            const int kbyt = ks * 64 + (l >> 4) * 16;
#pragma unroll
            for (int n = 0; n < 4; ++n)
                sc[n] = MFMA(qa[ks], fld(Ks, n * 16 + (l & 15), kbyt), sc[n]);
        }
        // wgt -> swizzled LDS P-tile (bf16)
#pragma unroll
        for (int n = 0; n < 4; ++n) {
            const int col = n * 16 + (l & 15);
            const int kp = kt * 64 + col;
#pragma unroll
            for (int r = 0; r < 4; ++r) {
                float s = sc[n][r] * 0.125f;
                if (kt == qt && kp > qrow + r) s = -3.0e38f;
                const float wgt = __expf(s - m4[r]) * inv[r];   // masked -> exact 0
                const int row = w * 16 + ((l >> 4) << 2) + r;
                int ofs = row * 128 + col * 2;
                ofs ^= ((row & 7) << 4);
                *(unsigned short*)(Ps + ofs) = f2bf(wgt);
            }
        }
        __syncthreads();                               // Ps visible
        // PV: acc_o += P @ V
#pragma unroll
        for (int ks = 0; ks < 2; ++ks) {
            const int kbyt = ks * 64 + (l >> 4) * 16;
            const bf16x8 pa = fld(Ps, w * 16 + (l & 15), kbyt);
#pragma unroll
            for (int n = 0; n < 4; ++n)
                acc_o[n] = MFMA(pa, fld(Vs, n * 16 + (l & 15), kbyt), acc_o[n]);
        }
        // coalesced fp32 attn store from Ps: 16 lanes cover one 256B row seg
#pragma unroll
        for (int rp = 0; rp < 4; ++rp) {
            const int row = rp * 16 + (tid >> 4);
            int ofs = row * 128 + (tid & 15) * 8;
            ofs ^= ((row & 7) << 4);
            const bf16x4 pv4 = *(const bf16x4*)(Ps + ofs);
            float4 f;
            f.x = bf2f((unsigned short)pv4[0]); f.y = bf2f((unsigned short)pv4[1]);
            f.z = bf2f((unsigned short)pv4[2]); f.w = bf2f((unsigned short)pv4[3]);
            *(float4*)(ab + (size_t)(i0 + row) * SS + kt * 64 + (tid & 15) * 4) = f;
        }
    }

    // ---- O -> ctx (coalesced via Ps reuse) ----
    __syncthreads();
#pragma unroll
    for (int n = 0; n < 4; ++n) {
        const int col = n * 16 + (l & 15);
#pragma unroll
        for (int r = 0; r < 4; ++r) {
            const int row = w * 16 + ((l >> 4) << 2) + r;
            int ofs = row * 128 + col * 2;
            ofs ^= ((row & 7) << 4);
            *(unsigned short*)(Ps + ofs) = f2bf(acc_o[n][r]);
        }
    }
    __syncthreads();
    const int b = bh >> 4, h = bh & 15;
#pragma unroll
    for (int rp = 0; rp < 4; ++rp) {
        const int row = rp * 16 + (tid >> 4);
        int ofs = row * 128 + (tid & 15) * 8;
        ofs ^= ((row & 7) << 4);
        const bf16x4 o4 = *(const bf16x4*)(Ps + ofs);
        *(bf16x4*)(ctx + (size_t)(b * SS + i0 + row) * D_MODEL + h * DKH + (tid & 15) * 4) = o4;
    }

    // ---- zero-fill causal upper region, row-contiguous float4 ----
    const int zs = (qt + 1) * 64;
    if (zs < SS) {
        const int nf4 = (SS - zs) >> 2;
        const float4 z4 = make_float4(0.f, 0.f, 0.f, 0.f);
        for (int r = 0; r < 64; ++r) {
            float4* dst = (float4*)(ab + (size_t)(i0 + r) * SS + zs);
            for (int c = tid; c < nf4; c += 256) dst[c] = z4;
        }
    }
}

// ---------------------------------------------------------------------------
// Output projection + residual: pre = ctx @ WO.T + resid  (fp32 out)
// ---------------------------------------------------------------------------
__global__ __launch_bounds__(256)
void k_oproj(const unsigned short* __restrict__ A, const unsigned short* __restrict__ B,
             const float* __restrict__ resid, float* __restrict__ ofp)
{
    __shared__ char lds[32768];
    const int tid = threadIdx.x;
    const int w = tid >> 6, l = tid & 63;
    const int n0 = blockIdx.x * 128, m0 = blockIdx.y * 128;
    const int wr = (w >> 1) * 64, wc = (w & 1) * 64;

    f32x4 acc[4][4] = {};

    for (int kt = 0; kt < 16; ++kt) {
        __syncthreads();
        stage128<4>(lds,         A + (size_t)m0 * 1024 + kt * 64, 1024, w, l);
        stage128<4>(lds + 16384, B + (size_t)n0 * 1024 + kt * 64, 1024, w, l);
        __syncthreads();
#pragma unroll
        for (int ks = 0; ks < 2; ++ks) {
            const int kb = ks * 64 + (l >> 4) * 16;
            bf16x8 av[4], bv[4];
#pragma unroll
            for (int i = 0; i < 4; ++i) av[i] = fld(lds,         wr + i * 16 + (l & 15), kb);
#pragma unroll
            for (int j = 0; j < 4; ++j) bv[j] = fld(lds + 16384, wc + j * 16 + (l & 15), kb);
#pragma unroll
            for (int i = 0; i < 4; ++i)
#pragma unroll
                for (int j = 0; j < 4; ++j)
                    acc[i][j] = MFMA(av[i], bv[j], acc[i][j]);
        }
    }

#pragma unroll
    for (int i = 0; i < 4; ++i)
#pragma unroll
        for (int j = 0; j < 4; ++j)
#pragma unroll
            for (int r = 0; r < 4; ++r) {
                const int m = m0 + wr + i * 16 + ((l >> 4) << 2) + r;
                const int n = n0 + wc + j * 16 + (l & 15);
                const size_t o = (size_t)m * 1024 + n;
                ofp[o] = acc[i][j][r] + resid[o];
            }
}

// ---------------------------------------------------------------------------
// LayerNorm per row of 1024.
// ---------------------------------------------------------------------------
__global__ __launch_bounds__(256)
void k_ln(const float* __restrict__ pre, const float* __restrict__ gamma,
          const float* __restrict__ beta, float* __restrict__ out)
{
    const int row = blockIdx.x;
    const int tid = threadIdx.x;
    const float* p = pre + (size_t)row * D_MODEL;
    float* o = out + (size_t)row * D_MODEL;

    __shared__ float red[4];

    float4 x = ((const float4*)p)[tid];
    float s = x.x + x.y + x.z + x.w;
#pragma unroll
    for (int off = 32; off; off >>= 1) s += __shfl_down(s, off);
    if ((tid & 63) == 0) red[tid >> 6] = s;
    __syncthreads();
    const float mu = (red[0] + red[1] + red[2] + red[3]) * (1.0f / D_MODEL);

    float dx[4] = {x.x - mu, x.y - mu, x.z - mu, x.w - mu};
    float ss = dx[0] * dx[0] + dx[1] * dx[1] + dx[2] * dx[2] + dx[3] * dx[3];
#pragma unroll
    for (int off = 32; off; off >>= 1) ss += __shfl_down(ss, off);
    __syncthreads();
    if ((tid & 63) == 0) red[tid >> 6] = ss;
    __syncthreads();
    const float var = (red[0] + red[1] + red[2] + red[3]) * (1.0f / D_MODEL);
    const float inv = rsqrtf(var + 1e-5f);

    const float4 g  = ((const float4*)gamma)[tid];
    const float4 be = ((const float4*)beta)[tid];
    ((float4*)o)[tid] = make_float4(dx[0] * inv * g.x + be.x, dx[1] * inv * g.y + be.y,
                                    dx[2] * inv * g.z + be.z, dx[3] * inv * g.w + be.w);
}

// ---------------------------------------------------------------------------
extern "C" void kernel_launch(void* const* d_in, const int* in_sizes, int n_in,
                              void* d_out, int out_size, void* d_ws, size_t ws_size,
                              hipStream_t stream)
{
    const float* Q     = (const float*)d_in[0];
    const float* K     = (const float*)d_in[1];
    const float* V     = (const float*)d_in[2];
    // d_in[3] = causal mask (known tril) -> unused
    const float* WQ    = (const float*)d_in[4];
    const float* WK    = (const float*)d_in[5];
    const float* WV    = (const float*)d_in[6];
    const float* WO    = (const float*)d_in[7];
    const float* gamma = (const float*)d_in[8];
    const float* beta  = (const float*)d_in[9];

    float* out  = (float*)d_out;                       // (B,S,D)
    float* attn = out + (size_t)BB * SS * D_MODEL;     // (B,H,S,S) fp32

    // ws layout:
    //   [0,32M)   bf16 cvt: Xq,Xk,Xv (4M elem) | Wq,Wk,Wv,Wo (1M elem)
    //   [32M,56M) Qh, Kh (b,h,s,dk) | VhT (b,h,dk,s)
    //   [56M,64M) ctx bf16 (m,1024)
    //   [64M,80M) preLN fp32
    char* ws = (char*)d_ws;
    unsigned short* cvt = (unsigned short*)ws;
    unsigned short* Xq = cvt;
    unsigned short* Xk = cvt + 4194304;
    unsigned short* Xv = cvt + 2 * 4194304;
    unsigned short* Wq = cvt + 3 * 4194304;
    unsigned short* Wk = Wq + 1048576;
    unsigned short* Wv = Wk + 1048576;
    unsigned short* Wo = Wv + 1048576;
    unsigned short* Qh  = (unsigned short*)(ws + 33554432);
    unsigned short* Kh  = Qh + 4194304;
    unsigned short* VhT = Kh + 4194304;
    unsigned short* ctx = (unsigned short*)(ws + 58720256);
    float*          pre = (float*)(ws + 67108864);

    k_cvt<<<dim3(8192), dim3(256), 0, stream>>>(Q, K, V, WQ, WK, WV, WO, cvt);
    k_qkv<<<dim3(8, 32, 3), dim3(256), 0, stream>>>(Xq, Xk, Xv, Wq, Wk, Wv, Qh, Kh, VhT);
    k_attn<<<dim3(32, 32), dim3(256), 0, stream>>>(Qh, Kh, VhT, attn, ctx);
    k_oproj<<<dim3(8, 32), dim3(256), 0, stream>>>(ctx, Wo, Q, pre);
    k_ln<<<dim3(MM), dim3(256), 0, stream>>>(pre, gamma, beta, out);
}